// Round 8
// baseline (1857.847 us; speedup 1.0000x reference)
//
#include <hip/hip_runtime.h>
#include <hip/hip_fp16.h>

#define N_VAR 256
#define M_CON 512
#define BATCH 64
#define SIGMA_C 1e-6f
#define RHO_C 0.1f
#define ALPHA_C 1.6f
#define NITERS 500

// ---------------------------------------------------------------------------
// K1: transpose A [512][256] -> At [256][512] per batch
// ---------------------------------------------------------------------------
__global__ __launch_bounds__(256) void k_transpose(const float* __restrict__ A,
                                                   float* __restrict__ At) {
  __shared__ float tile[32][33];
  int b = blockIdx.z;
  int n0 = blockIdx.x * 32;
  int m0 = blockIdx.y * 32;
  const float* Ab = A + (size_t)b * (M_CON * N_VAR);
  float* Atb = At + (size_t)b * (M_CON * N_VAR);
  int tx = threadIdx.x, ty = threadIdx.y;  // (32, 8)
#pragma unroll
  for (int j = 0; j < 32; j += 8)
    tile[ty + j][tx] = Ab[(size_t)(m0 + ty + j) * N_VAR + n0 + tx];
  __syncthreads();
#pragma unroll
  for (int j = 0; j < 32; j += 8)
    Atb[(size_t)(n0 + ty + j) * M_CON + m0 + tx] = tile[tx][ty + j];
}

// ---------------------------------------------------------------------------
// K2: batched NT GEMM  C[i][j] = alpha * sum_k X[i][k]*Y[j][k]  (+ diag)
// ---------------------------------------------------------------------------
__global__ __launch_bounds__(256) void k_ntgemm(
    const float* __restrict__ X, const float* __restrict__ Y,
    float* __restrict__ C, int I, int J, int K,
    long long bsX, long long bsY, long long bsC, float alpha,
    const float* __restrict__ diagv, int tilesJ) {
  int b = blockIdx.y;
  int ti = blockIdx.x / tilesJ, tj = blockIdx.x % tilesJ;
  int i0 = ti * 128, j0 = tj * 128;
  const float* Xb = X + (size_t)b * bsX;
  const float* Yb = Y + (size_t)b * bsY;
  float* Cb = C + (size_t)b * bsC;
  __shared__ float Xs[16][128];
  __shared__ float Ys[16][128];
  int tid = threadIdx.x;
  int tx = tid & 15, ty = tid >> 4;
  float acc[8][8];
#pragma unroll
  for (int r = 0; r < 8; ++r)
#pragma unroll
    for (int c = 0; c < 8; ++c) acc[r][c] = 0.0f;

  for (int kk = 0; kk < K; kk += 16) {
#pragma unroll
    for (int v = 0; v < 2; ++v) {
      int idx = v * 256 + tid;
      int row = idx >> 2;
      int k4 = (idx & 3) * 4;
      float4 gx = *(const float4*)(Xb + (size_t)(i0 + row) * K + kk + k4);
      Xs[k4 + 0][row] = gx.x; Xs[k4 + 1][row] = gx.y;
      Xs[k4 + 2][row] = gx.z; Xs[k4 + 3][row] = gx.w;
      float4 gy = *(const float4*)(Yb + (size_t)(j0 + row) * K + kk + k4);
      Ys[k4 + 0][row] = gy.x; Ys[k4 + 1][row] = gy.y;
      Ys[k4 + 2][row] = gy.z; Ys[k4 + 3][row] = gy.w;
    }
    __syncthreads();
#pragma unroll
    for (int k = 0; k < 16; ++k) {
      float xr[8], yr[8];
      *(float4*)&xr[0] = *(float4*)&Xs[k][ty * 8];
      *(float4*)&xr[4] = *(float4*)&Xs[k][ty * 8 + 4];
      *(float4*)&yr[0] = *(float4*)&Ys[k][tx * 8];
      *(float4*)&yr[4] = *(float4*)&Ys[k][tx * 8 + 4];
#pragma unroll
      for (int r = 0; r < 8; ++r)
#pragma unroll
        for (int c = 0; c < 8; ++c) acc[r][c] += xr[r] * yr[c];
    }
    __syncthreads();
  }
#pragma unroll
  for (int r = 0; r < 8; ++r) {
    int gi = i0 + ty * 8 + r;
#pragma unroll
    for (int c = 0; c < 8; ++c) {
      int gj = j0 + tx * 8 + c;
      float val = acc[r][c] * alpha;
      if (diagv != nullptr && gi == gj) val += diagv[(size_t)b * N_VAR + gi] + SIGMA_C;
      Cb[(size_t)gi * J + gj] = val;
    }
  }
}

// ---------------------------------------------------------------------------
// K3: BLOCKED Gauss-Jordan inversion, NB=8 (round-7 version; out of top-5).
// ---------------------------------------------------------------------------
__global__ __launch_bounds__(512, 2) void k_invert(const float* __restrict__ Mk,
                                                   float* __restrict__ Mi) {
  int b = blockIdx.x;
  const float* src = Mk + (size_t)b * 65536;
  float* dst = Mi + (size_t)b * 65536;
  int t = threadIdx.x;
  int c = t & 255, rh = t >> 8;

  float a[128];
#pragma unroll
  for (int j = 0; j < 128; ++j) a[j] = src[(size_t)(rh * 128 + j) * 256 + c];

  __shared__ float colPan[256][8];
  __shared__ float rowPan[2][8][260];
  __shared__ float PiSh[64];
  __shared__ float Rp[8][260];

  int rh_s = __builtin_amdgcn_readfirstlane(rh);
  int cw_s = __builtin_amdgcn_readfirstlane((t >> 6) & 3);

  if (rh == 0) {
#pragma unroll
    for (int j = 0; j < 8; ++j) rowPan[0][j][c] = a[j];
  }
  __syncthreads();

  for (int s = 0; s < 32; ++s) {
    int kb = s * 8;
    int cur = s & 1, nxt = cur ^ 1;
    int kh = kb >> 7, kj = kb & 127;
    int khn = (kb + 8) >> 7, kjn = (kb + 8) & 127;
    bool mycol = (c >= kb) && (c < kb + 8);

    if (cw_s == (kb >> 6)) {
      if (mycol) {
        int f = c - kb;
#pragma unroll
        for (int j = 0; j < 128; ++j) colPan[rh * 128 + j][f] = a[j];
      }
    }
    if (t < 64) {
      int e = t >> 3, f = t & 7;
      float p = rowPan[cur][e][kb + f];
#pragma unroll
      for (int k2 = 0; k2 < 8; ++k2) {
        float piv = __shfl(p, k2 * 8 + k2);
        float rv = __shfl(p, k2 * 8 + f);
        float cv = __shfl(p, e * 8 + k2);
        float pivinv = 1.0f / piv;
        float srv = rv * pivinv;
        float gen = p - cv * srv;
        p = gen;
        if (e == k2) p = srv;
        if (f == k2) p = -cv * pivinv;
        if (e == k2 && f == k2) p = pivinv;
      }
      PiSh[t] = p;
    }
    __syncthreads();

    float rpan[8];
#pragma unroll
    for (int f2 = 0; f2 < 8; ++f2) rpan[f2] = rowPan[cur][f2][c];
    float rp[8];
#pragma unroll
    for (int e = 0; e < 8; ++e) {
      float4 p0 = *(const float4*)&PiSh[e * 8];
      float4 p1 = *(const float4*)&PiSh[e * 8 + 4];
      rp[e] = p0.x * rpan[0] + p0.y * rpan[1] + p0.z * rpan[2] + p0.w * rpan[3] +
              p1.x * rpan[4] + p1.y * rpan[5] + p1.z * rpan[6] + p1.w * rpan[7];
    }
    if (cw_s == (kb >> 6)) {
      if (mycol) {
        int f = c - kb;
#pragma unroll
        for (int e = 0; e < 8; ++e) rp[e] = PiSh[e * 8 + f];
      }
    }
#pragma unroll
    for (int e = 0; e < 8; ++e) Rp[e][c] = rp[e];

    bool myhalfk = (rh_s == kh);
    bool stashw = (s != 31) && (rh_s == khn);
#pragma unroll
    for (int j = 0; j < 128; ++j) {
      float4 c0 = *(const float4*)&colPan[rh * 128 + j][0];
      float4 c1 = *(const float4*)&colPan[rh * 128 + j][4];
      float aold = a[j];
      float nv = aold -
                 (c0.x * rp[0] + c0.y * rp[1] + c0.z * rp[2] + c0.w * rp[3] +
                  c1.x * rp[4] + c1.y * rp[5] + c1.z * rp[6] + c1.w * rp[7]);
      if (mycol) nv -= aold;
      if (myhalfk && j >= kj && j < kj + 8)
        nv = Rp[j - kj][c];
      a[j] = nv;
      if (stashw && j >= kjn && j < kjn + 8)
        rowPan[nxt][j - kjn][c] = nv;
    }
    __syncthreads();
  }

#pragma unroll
  for (int j = 0; j < 128; ++j) dst[(size_t)(rh * 128 + j) * 256 + c] = a[j];
}

// ---------------------------------------------------------------------------
// K4a: h = Minv * q  (column access via symmetry)
// ---------------------------------------------------------------------------
__global__ __launch_bounds__(256) void k_matvec_h(const float* __restrict__ Mi,
                                                  const float* __restrict__ q,
                                                  float* __restrict__ h) {
  int b = blockIdx.x, t = threadIdx.x;
  __shared__ float qs[256];
  qs[t] = q[(size_t)b * 256 + t];
  __syncthreads();
  const float* Mb = Mi + (size_t)b * 65536;
  float acc = 0.0f;
  for (int k = 0; k < 256; ++k) acc += Mb[(size_t)k * 256 + t] * qs[k];
  h[(size_t)b * 256 + t] = acc;
}

// K4b: d = A * h  via At columns
__global__ __launch_bounds__(512) void k_matvec_d(const float* __restrict__ At,
                                                  const float* __restrict__ h,
                                                  float* __restrict__ d) {
  int b = blockIdx.x, t = threadIdx.x;
  __shared__ float hs[256];
  if (t < 256) hs[t] = h[(size_t)b * 256 + t];
  __syncthreads();
  const float* Ab = At + (size_t)b * 131072;
  float acc = 0.0f;
  for (int n = 0; n < 256; ++n) acc += Ab[(size_t)n * 512 + t] * hs[n];
  d[(size_t)b * 512 + t] = acc;
}

// ---------------------------------------------------------------------------
// K6: ADMM loop, 2-BATCH INTERLEAVE. 8 slices/batch (8 CUs), 2 batches/WG:
// batch A's cross-CU transport is hidden behind batch B's compute.
// Grid 256 WGs x 512 thr: pair p=g&31, slice s=g>>5 (g%8==p%8 -> a pair's 8
// slices share an XCD under round-robin dispatch; perf heuristic only).
// Thread: row s*64+(t&63), cols [(t>>6)*64, +64) -> 64 G-floats per batch,
// 128 total (+state ~160 regs < 256 cap; 1 WG/CU -> 256 co-resident WGs,
// spin-sync deadlock-free). Exchange: round-6 packed (tag<<32|float) u64
// relaxed agent atomics, parity double-buffered; 448 pollers cover the 448
// remote rows, one slot each. 4 barriers per iteration-PAIR.
// ---------------------------------------------------------------------------
__global__ __launch_bounds__(512, 2) void k_admm8(
    const float* __restrict__ G, const float* __restrict__ dvec,
    const float* __restrict__ lv, const float* __restrict__ uv,
    unsigned long long* __restrict__ wtag, float* __restrict__ Sbuf) {
  int g = blockIdx.x;
  int p = g & 31;
  int s = g >> 5;
  int b0 = 2 * p, b1 = 2 * p + 1;
  int t = threadIdx.x;
  int l = t & 63, wv = t >> 6;
  int c0 = wv * 64;
  int row = s * 64 + l;

  __shared__ __align__(16) float wlA[512], wlB[512];
  __shared__ float pA[8][64], pB[8][64];

  // --- one-time: G strips (both batches) into registers/AGPRs ---
  const float* gAp = G + (size_t)b0 * 262144 + (size_t)row * 512 + c0;
  const float* gBp = G + (size_t)b1 * 262144 + (size_t)row * 512 + c0;
  float GA[64], GB[64];
#pragma unroll
  for (int j = 0; j < 16; ++j) {
    float4 va = *(const float4*)(gAp + 4 * j);
    GA[4 * j + 0] = va.x; GA[4 * j + 1] = va.y;
    GA[4 * j + 2] = va.z; GA[4 * j + 3] = va.w;
    float4 vb = *(const float4*)(gBp + 4 * j);
    GB[4 * j + 0] = vb.x; GB[4 * j + 1] = vb.y;
    GB[4 * j + 2] = vb.z; GB[4 * j + 3] = vb.w;
  }

  float zA = 0, yA = 0, SA = 0, lA = 0, uA = 0, dA = 0;
  float zB = 0, yB = 0, SB = 0, lB = 0, uB = 0, dB = 0;
  if (t < 64) {
    int m = s * 64 + t;
    lA = lv[(size_t)b0 * 512 + m]; uA = uv[(size_t)b0 * 512 + m];
    dA = dvec[(size_t)b0 * 512 + m];
    lB = lv[(size_t)b1 * 512 + m]; uB = uv[(size_t)b1 * 512 + m];
    dB = dvec[(size_t)b1 * 512 + m];
  }
  wlA[t] = 0.0f;  // w_0 = 0
  wlB[t] = 0.0f;

  unsigned long long* A0 = wtag + (size_t)b0 * 512;
  unsigned long long* A1 = wtag + 32768 + (size_t)b0 * 512;
  unsigned long long* B0 = wtag + (size_t)b1 * 512;
  unsigned long long* B1 = wtag + 32768 + (size_t)b1 * 512;
  int pr = (s * 64 + 64 + (t - 64)) & 511;  // poll target row (t>=64)

  const float4* wqA = (const float4*)(wlA + c0);
  const float4* wqB = (const float4*)(wlB + c0);

  for (int it = 0; it < NITERS; ++it) {
    __syncthreads();  // Btop: wlA == w_it(A), wlB == w_it(B)
    bool more = (it < NITERS - 1);
    unsigned want = (unsigned)(it + 1);

    // ---- GEMV A: row `row`, cols [c0,c0+64) ----
    float accA = 0.0f;
#pragma unroll
    for (int j = 0; j < 16; ++j) {
      float4 w4 = wqA[j];  // uniform-address ds_read_b128 (broadcast)
      accA += GA[4 * j + 0] * w4.x + GA[4 * j + 1] * w4.y +
              GA[4 * j + 2] * w4.z + GA[4 * j + 3] * w4.w;
    }
    pA[wv][l] = accA;
    __syncthreads();  // B1: pA ready

    // ---- update A (t<64) + publish; everyone: GEMV B ----
    if (t < 64) {
      float w_old = RHO_C * zA - yA;
      SA = w_old - 0.6f * SA;
      float zt = pA[0][t] + pA[1][t] + pA[2][t] + pA[3][t] +
                 pA[4][t] + pA[5][t] + pA[6][t] + pA[7][t] - dA;
      float zh = ALPHA_C * zt + (1.0f - ALPHA_C) * zA;
      float zc = fminf(fmaxf(zh + yA * (1.0f / RHO_C), lA), uA);
      yA += RHO_C * (zh - zc);
      zA = zc;
      float wn = RHO_C * zA - yA;
      wlA[s * 64 + t] = wn;
      if (more) {
        unsigned long long pk = ((unsigned long long)want << 32) |
                                (unsigned long long)__float_as_uint(wn);
        unsigned long long* wp = ((it + 1) & 1) ? A1 : A0;
        __hip_atomic_store(&wp[s * 64 + t], pk, __ATOMIC_RELAXED,
                           __HIP_MEMORY_SCOPE_AGENT);
      }
    }
    float accB = 0.0f;
#pragma unroll
    for (int j = 0; j < 16; ++j) {
      float4 w4 = wqB[j];
      accB += GB[4 * j + 0] * w4.x + GB[4 * j + 1] * w4.y +
              GB[4 * j + 2] * w4.z + GB[4 * j + 3] * w4.w;
    }
    pB[wv][l] = accB;
    __syncthreads();  // B2: pB ready; wlA own rows written

    // ---- update B (t<64) + publish; pollers fetch remote A ----
    if (t < 64) {
      float w_old = RHO_C * zB - yB;
      SB = w_old - 0.6f * SB;
      float zt = pB[0][t] + pB[1][t] + pB[2][t] + pB[3][t] +
                 pB[4][t] + pB[5][t] + pB[6][t] + pB[7][t] - dB;
      float zh = ALPHA_C * zt + (1.0f - ALPHA_C) * zB;
      float zc = fminf(fmaxf(zh + yB * (1.0f / RHO_C), lB), uB);
      yB += RHO_C * (zh - zc);
      zB = zc;
      float wn = RHO_C * zB - yB;
      wlB[s * 64 + t] = wn;
      if (more) {
        unsigned long long pk = ((unsigned long long)want << 32) |
                                (unsigned long long)__float_as_uint(wn);
        unsigned long long* wp = ((it + 1) & 1) ? B1 : B0;
        __hip_atomic_store(&wp[s * 64 + t], pk, __ATOMIC_RELAXED,
                           __HIP_MEMORY_SCOPE_AGENT);
      }
    } else if (more) {
      unsigned long long* wp = ((it + 1) & 1) ? A1 : A0;
      unsigned long long v;
      for (;;) {
        v = __hip_atomic_load(&wp[pr], __ATOMIC_RELAXED,
                              __HIP_MEMORY_SCOPE_AGENT);
        if ((unsigned)(v >> 32) == want) break;
        __builtin_amdgcn_s_sleep(1);
      }
      wlA[pr] = __uint_as_float((unsigned)(v & 0xffffffffu));
    }
    __syncthreads();  // B3: wlA complete; wlB own rows written

    if (more && t >= 64) {  // pollers fetch remote B (transport overlapped)
      unsigned long long* wp = ((it + 1) & 1) ? B1 : B0;
      unsigned long long v;
      for (;;) {
        v = __hip_atomic_load(&wp[pr], __ATOMIC_RELAXED,
                              __HIP_MEMORY_SCOPE_AGENT);
        if ((unsigned)(v >> 32) == want) break;
        __builtin_amdgcn_s_sleep(1);
      }
      wlB[pr] = __uint_as_float((unsigned)(v & 0xffffffffu));
    }
    // loop-top barrier seals wlB
  }

  if (t < 64) {
    Sbuf[(size_t)b0 * 512 + s * 64 + t] = SA;
    Sbuf[(size_t)b1 * 512 + s * 64 + t] = SB;
  }
}

// ---------------------------------------------------------------------------
// K7: epilogue  x = Minv * (alpha * A^T S - q)
// ---------------------------------------------------------------------------
__global__ __launch_bounds__(256) void k_final(
    const float* __restrict__ A, const float* __restrict__ q,
    const float* __restrict__ Mi, const float* __restrict__ Sbuf,
    float* __restrict__ xout) {
  int b = blockIdx.x, t = threadIdx.x;
  __shared__ float Ssh[512];
  __shared__ float uu[256];
  for (int i = t; i < 512; i += 256) Ssh[i] = Sbuf[(size_t)b * 512 + i];
  __syncthreads();
  const float* Ab = A + (size_t)b * 131072;
  float acc = 0.0f;
  for (int m = 0; m < 512; ++m) acc += Ab[(size_t)m * 256 + t] * Ssh[m];
  uu[t] = ALPHA_C * acc - q[(size_t)b * 256 + t];
  __syncthreads();
  const float* Mb = Mi + (size_t)b * 65536;
  float x = 0.0f;
  for (int kk = 0; kk < 256; ++kk) x += Mb[(size_t)kk * 256 + t] * uu[kk];
  xout[(size_t)b * 256 + t] = x;
}

// ---------------------------------------------------------------------------
extern "C" void kernel_launch(void* const* d_in, const int* in_sizes, int n_in,
                              void* d_out, int out_size, void* d_ws, size_t ws_size,
                              hipStream_t stream) {
  (void)in_sizes; (void)n_in; (void)out_size; (void)ws_size;
  const float* P = (const float*)d_in[0];
  const float* q = (const float*)d_in[1];
  const float* Av = (const float*)d_in[2];
  const float* lv = (const float*)d_in[3];
  const float* uv = (const float*)d_in[4];
  float* xout = (float*)d_out;

  float* ws = (float*)d_ws;
  float* At = ws;                       // 64*256*512; dies after k_matvec_d
  float* F  = ws;                       // alias of At; dies after ntgemm G
  float* Mi = ws + 8388608;             // 64*256*256
  float* Mk = ws + 12582912;            // dies after k_invert
  float* G  = ws + 12582912;            // 64*512*512 (over dead Mk)
  float* hv = ws + 29360128;            // 64*256
  float* dv = ws + 29376512;            // 64*512
  float* Sbuf = ws + 29409280;          // 64*512
  unsigned long long* wtag = (unsigned long long*)ws;  // overlays dead At/F

  k_transpose<<<dim3(8, 16, 64), dim3(32, 8), 0, stream>>>(Av, At);
  k_ntgemm<<<dim3(4, 64), 256, 0, stream>>>(At, At, Mk, 256, 256, 512,
                                            131072LL, 131072LL, 65536LL,
                                            RHO_C, P, 2);
  k_invert<<<64, 512, 0, stream>>>(Mk, Mi);
  k_matvec_h<<<64, 256, 0, stream>>>(Mi, q, hv);
  k_matvec_d<<<64, 512, 0, stream>>>(At, hv, dv);
  k_ntgemm<<<dim3(8, 64), 256, 0, stream>>>(Av, Mi, F, 512, 256, 256,
                                            131072LL, 65536LL, 131072LL,
                                            1.0f, nullptr, 2);
  k_ntgemm<<<dim3(16, 64), 256, 0, stream>>>(F, Av, G, 512, 512, 256,
                                             131072LL, 131072LL, 262144LL,
                                             1.0f, nullptr, 4);
  k_admm8<<<256, 512, 0, stream>>>(G, dv, lv, uv, wtag, Sbuf);
  k_final<<<64, 256, 0, stream>>>(Av, q, Mi, Sbuf, xout);
}

// Round 9
// 1741.651 us; speedup vs baseline: 1.0667x; 1.0667x over previous
//
#include <hip/hip_runtime.h>
#include <hip/hip_fp16.h>

#define N_VAR 256
#define M_CON 512
#define BATCH 64
#define SIGMA_C 1e-6f
#define RHO_C 0.1f
#define ALPHA_C 1.6f
#define NITERS 500

// ---------------------------------------------------------------------------
// K1: transpose A [512][256] -> At [256][512] per batch
// ---------------------------------------------------------------------------
__global__ __launch_bounds__(256) void k_transpose(const float* __restrict__ A,
                                                   float* __restrict__ At) {
  __shared__ float tile[32][33];
  int b = blockIdx.z;
  int n0 = blockIdx.x * 32;
  int m0 = blockIdx.y * 32;
  const float* Ab = A + (size_t)b * (M_CON * N_VAR);
  float* Atb = At + (size_t)b * (M_CON * N_VAR);
  int tx = threadIdx.x, ty = threadIdx.y;  // (32, 8)
#pragma unroll
  for (int j = 0; j < 32; j += 8)
    tile[ty + j][tx] = Ab[(size_t)(m0 + ty + j) * N_VAR + n0 + tx];
  __syncthreads();
#pragma unroll
  for (int j = 0; j < 32; j += 8)
    Atb[(size_t)(n0 + ty + j) * M_CON + m0 + tx] = tile[tx][ty + j];
}

// ---------------------------------------------------------------------------
// K2: batched NT GEMM, DOUBLE-BUFFERED LDS + optional symmetric-upper tiling.
// C[i][j] = alpha * sum_k X[i][k]*Y[j][k] (+ diag). 128x128 tile, 256 thr,
// 8x8 acc. symN>0: blockIdx.x enumerates upper tiles (ti<=tj) of an
// symN x symN tile grid; lower tiles are filled by k_mirror afterwards.
// Prefetch k-tile kt+1 to VGPRs during compute of kt; commit to alt buffer.
// ---------------------------------------------------------------------------
__global__ __launch_bounds__(256) void k_ntgemm(
    const float* __restrict__ X, const float* __restrict__ Y,
    float* __restrict__ C, int J, int K,
    long long bsX, long long bsY, long long bsC, float alpha,
    const float* __restrict__ diagv, int tilesJ, int symN) {
  int b = blockIdx.y;
  int ti, tj;
  if (symN > 0) {
    int r = blockIdx.x;
    ti = 0;
    while (r >= symN - ti) { r -= (symN - ti); ++ti; }
    tj = ti + r;
  } else {
    ti = blockIdx.x / tilesJ;
    tj = blockIdx.x % tilesJ;
  }
  int i0 = ti * 128, j0 = tj * 128;
  const float* Xb = X + (size_t)b * bsX;
  const float* Yb = Y + (size_t)b * bsY;
  float* Cb = C + (size_t)b * bsC;
  __shared__ float Xs[2][16][128];
  __shared__ float Ys[2][16][128];
  int tid = threadIdx.x;
  int tx = tid & 15, ty = tid >> 4;
  int row0 = tid >> 2, k40 = (tid & 3) * 4;  // staging coords (v=0; v=1 is row0+64)

  float acc[8][8];
#pragma unroll
  for (int r = 0; r < 8; ++r)
#pragma unroll
    for (int c = 0; c < 8; ++c) acc[r][c] = 0.0f;

  float4 rx0, rx1, ry0, ry1;
  // prefetch k-tile at offset kk into registers
  auto prefetch = [&](int kk) {
    rx0 = *(const float4*)(Xb + (size_t)(i0 + row0) * K + kk + k40);
    rx1 = *(const float4*)(Xb + (size_t)(i0 + row0 + 64) * K + kk + k40);
    ry0 = *(const float4*)(Yb + (size_t)(j0 + row0) * K + kk + k40);
    ry1 = *(const float4*)(Yb + (size_t)(j0 + row0 + 64) * K + kk + k40);
  };
  auto commit = [&](int buf) {
    Xs[buf][k40 + 0][row0] = rx0.x; Xs[buf][k40 + 1][row0] = rx0.y;
    Xs[buf][k40 + 2][row0] = rx0.z; Xs[buf][k40 + 3][row0] = rx0.w;
    Xs[buf][k40 + 0][row0 + 64] = rx1.x; Xs[buf][k40 + 1][row0 + 64] = rx1.y;
    Xs[buf][k40 + 2][row0 + 64] = rx1.z; Xs[buf][k40 + 3][row0 + 64] = rx1.w;
    Ys[buf][k40 + 0][row0] = ry0.x; Ys[buf][k40 + 1][row0] = ry0.y;
    Ys[buf][k40 + 2][row0] = ry0.z; Ys[buf][k40 + 3][row0] = ry0.w;
    Ys[buf][k40 + 0][row0 + 64] = ry1.x; Ys[buf][k40 + 1][row0 + 64] = ry1.y;
    Ys[buf][k40 + 2][row0 + 64] = ry1.z; Ys[buf][k40 + 3][row0 + 64] = ry1.w;
  };

  int nkt = K >> 4;
  prefetch(0);
  commit(0);
  __syncthreads();

  for (int kt = 0; kt < nkt; ++kt) {
    int cur = kt & 1;
    if (kt + 1 < nkt) prefetch((kt + 1) * 16);  // global loads in flight
#pragma unroll
    for (int k = 0; k < 16; ++k) {
      float xr[8], yr[8];
      *(float4*)&xr[0] = *(float4*)&Xs[cur][k][ty * 8];
      *(float4*)&xr[4] = *(float4*)&Xs[cur][k][ty * 8 + 4];
      *(float4*)&yr[0] = *(float4*)&Ys[cur][k][tx * 8];
      *(float4*)&yr[4] = *(float4*)&Ys[cur][k][tx * 8 + 4];
#pragma unroll
      for (int r = 0; r < 8; ++r)
#pragma unroll
        for (int c = 0; c < 8; ++c) acc[r][c] += xr[r] * yr[c];
    }
    if (kt + 1 < nkt) commit(cur ^ 1);  // write alt buffer (no one reads it yet)
    __syncthreads();
  }

#pragma unroll
  for (int r = 0; r < 8; ++r) {
    int gi = i0 + ty * 8 + r;
#pragma unroll
    for (int c = 0; c < 8; ++c) {
      int gj = j0 + tx * 8 + c;
      float val = acc[r][c] * alpha;
      if (diagv != nullptr && gi == gj) val += diagv[(size_t)b * N_VAR + gi] + SIGMA_C;
      Cb[(size_t)gi * J + gj] = val;
    }
  }
}

// ---------------------------------------------------------------------------
// K2b: mirror upper triangle -> lower for symmetric n x n (32x32 subtiles,
// coalesced LDS transpose). blockIdx.x enumerates strict-lower 32-block
// pairs (bi>bj): idx = bi*(bi-1)/2 + bj.
// ---------------------------------------------------------------------------
__global__ __launch_bounds__(256) void k_mirror(float* __restrict__ C, int n,
                                                long long bsC) {
  __shared__ float tile[32][33];
  int b = blockIdx.y;
  int idx = blockIdx.x;
  int bi = 1;
  while (idx >= bi) { idx -= bi; ++bi; }
  int bj = idx;
  float* Cb = C + (size_t)b * bsC;
  int tx = threadIdx.x & 31, ty = threadIdx.x >> 5;  // 32 x 8
#pragma unroll
  for (int j = 0; j < 32; j += 8)
    tile[ty + j][tx] = Cb[(size_t)(bj * 32 + ty + j) * n + bi * 32 + tx];
  __syncthreads();
#pragma unroll
  for (int j = 0; j < 32; j += 8)
    Cb[(size_t)(bi * 32 + ty + j) * n + bj * 32 + tx] = tile[tx][ty + j];
}

// ---------------------------------------------------------------------------
// K3: BLOCKED Gauss-Jordan inversion, NB=8 (round-7 version; out of top-5).
// ---------------------------------------------------------------------------
__global__ __launch_bounds__(512, 2) void k_invert(const float* __restrict__ Mk,
                                                   float* __restrict__ Mi) {
  int b = blockIdx.x;
  const float* src = Mk + (size_t)b * 65536;
  float* dst = Mi + (size_t)b * 65536;
  int t = threadIdx.x;
  int c = t & 255, rh = t >> 8;

  float a[128];
#pragma unroll
  for (int j = 0; j < 128; ++j) a[j] = src[(size_t)(rh * 128 + j) * 256 + c];

  __shared__ float colPan[256][8];
  __shared__ float rowPan[2][8][260];
  __shared__ float PiSh[64];
  __shared__ float Rp[8][260];

  int rh_s = __builtin_amdgcn_readfirstlane(rh);
  int cw_s = __builtin_amdgcn_readfirstlane((t >> 6) & 3);

  if (rh == 0) {
#pragma unroll
    for (int j = 0; j < 8; ++j) rowPan[0][j][c] = a[j];
  }
  __syncthreads();

  for (int s = 0; s < 32; ++s) {
    int kb = s * 8;
    int cur = s & 1, nxt = cur ^ 1;
    int kh = kb >> 7, kj = kb & 127;
    int khn = (kb + 8) >> 7, kjn = (kb + 8) & 127;
    bool mycol = (c >= kb) && (c < kb + 8);

    if (cw_s == (kb >> 6)) {
      if (mycol) {
        int f = c - kb;
#pragma unroll
        for (int j = 0; j < 128; ++j) colPan[rh * 128 + j][f] = a[j];
      }
    }
    if (t < 64) {
      int e = t >> 3, f = t & 7;
      float p = rowPan[cur][e][kb + f];
#pragma unroll
      for (int k2 = 0; k2 < 8; ++k2) {
        float piv = __shfl(p, k2 * 8 + k2);
        float rv = __shfl(p, k2 * 8 + f);
        float cv = __shfl(p, e * 8 + k2);
        float pivinv = 1.0f / piv;
        float srv = rv * pivinv;
        float gen = p - cv * srv;
        p = gen;
        if (e == k2) p = srv;
        if (f == k2) p = -cv * pivinv;
        if (e == k2 && f == k2) p = pivinv;
      }
      PiSh[t] = p;
    }
    __syncthreads();

    float rpan[8];
#pragma unroll
    for (int f2 = 0; f2 < 8; ++f2) rpan[f2] = rowPan[cur][f2][c];
    float rp[8];
#pragma unroll
    for (int e = 0; e < 8; ++e) {
      float4 p0 = *(const float4*)&PiSh[e * 8];
      float4 p1 = *(const float4*)&PiSh[e * 8 + 4];
      rp[e] = p0.x * rpan[0] + p0.y * rpan[1] + p0.z * rpan[2] + p0.w * rpan[3] +
              p1.x * rpan[4] + p1.y * rpan[5] + p1.z * rpan[6] + p1.w * rpan[7];
    }
    if (cw_s == (kb >> 6)) {
      if (mycol) {
        int f = c - kb;
#pragma unroll
        for (int e = 0; e < 8; ++e) rp[e] = PiSh[e * 8 + f];
      }
    }
#pragma unroll
    for (int e = 0; e < 8; ++e) Rp[e][c] = rp[e];

    bool myhalfk = (rh_s == kh);
    bool stashw = (s != 31) && (rh_s == khn);
#pragma unroll
    for (int j = 0; j < 128; ++j) {
      float4 c0 = *(const float4*)&colPan[rh * 128 + j][0];
      float4 c1 = *(const float4*)&colPan[rh * 128 + j][4];
      float aold = a[j];
      float nv = aold -
                 (c0.x * rp[0] + c0.y * rp[1] + c0.z * rp[2] + c0.w * rp[3] +
                  c1.x * rp[4] + c1.y * rp[5] + c1.z * rp[6] + c1.w * rp[7]);
      if (mycol) nv -= aold;
      if (myhalfk && j >= kj && j < kj + 8)
        nv = Rp[j - kj][c];
      a[j] = nv;
      if (stashw && j >= kjn && j < kjn + 8)
        rowPan[nxt][j - kjn][c] = nv;
    }
    __syncthreads();
  }

#pragma unroll
  for (int j = 0; j < 128; ++j) dst[(size_t)(rh * 128 + j) * 256 + c] = a[j];
}

// ---------------------------------------------------------------------------
// K4a: h = Minv * q  (column access via symmetry)
// ---------------------------------------------------------------------------
__global__ __launch_bounds__(256) void k_matvec_h(const float* __restrict__ Mi,
                                                  const float* __restrict__ q,
                                                  float* __restrict__ h) {
  int b = blockIdx.x, t = threadIdx.x;
  __shared__ float qs[256];
  qs[t] = q[(size_t)b * 256 + t];
  __syncthreads();
  const float* Mb = Mi + (size_t)b * 65536;
  float acc = 0.0f;
  for (int k = 0; k < 256; ++k) acc += Mb[(size_t)k * 256 + t] * qs[k];
  h[(size_t)b * 256 + t] = acc;
}

// K4b: d = A * h  via At columns
__global__ __launch_bounds__(512) void k_matvec_d(const float* __restrict__ At,
                                                  const float* __restrict__ h,
                                                  float* __restrict__ d) {
  int b = blockIdx.x, t = threadIdx.x;
  __shared__ float hs[256];
  if (t < 256) hs[t] = h[(size_t)b * 256 + t];
  __syncthreads();
  const float* Ab = At + (size_t)b * 131072;
  float acc = 0.0f;
  for (int n = 0; n < 256; ++n) acc += Ab[(size_t)n * 512 + t] * hs[n];
  d[(size_t)b * 512 + t] = acc;
}

// ---------------------------------------------------------------------------
// K6: ADMM loop — ROUND-7 k_admm4 REVERT (765 us proven; the round-8 2-batch
// interleave regressed: batch B's poll had nothing to hide behind).
// 4 CUs/batch, register-resident G, packed (tag|value) u64 relaxed
// agent-atomic exchange, parity double-buffered. 2 barriers/iter.
// ---------------------------------------------------------------------------
__global__ __launch_bounds__(512, 2) void k_admm4(
    const float* __restrict__ G, const float* __restrict__ dvec,
    const float* __restrict__ lv, const float* __restrict__ uv,
    unsigned long long* __restrict__ wtag, float* __restrict__ Sbuf) {
  int g = blockIdx.x;
  int b = (g & 7) + 8 * ((g >> 3) & 7);
  int s = g >> 6;
  int t = threadIdx.x;
  int l = t & 63, wv = t >> 6;
  int c0 = wv * 64;

  __shared__ __align__(16) float wloc[512];
  __shared__ float part[8][128];

  const float* Gb = G + (size_t)b * 262144;
  const float* g0p = Gb + (size_t)(s * 128 + l) * 512 + c0;
  const float* g1p = Gb + (size_t)(s * 128 + 64 + l) * 512 + c0;
  float G0[64], G1[64];
#pragma unroll
  for (int j = 0; j < 16; ++j) {
    float4 v0 = *(const float4*)(g0p + 4 * j);
    G0[4 * j + 0] = v0.x; G0[4 * j + 1] = v0.y;
    G0[4 * j + 2] = v0.z; G0[4 * j + 3] = v0.w;
    float4 v1 = *(const float4*)(g1p + 4 * j);
    G1[4 * j + 0] = v1.x; G1[4 * j + 1] = v1.y;
    G1[4 * j + 2] = v1.z; G1[4 * j + 3] = v1.w;
  }

  float zreg = 0.0f, yreg = 0.0f, Sreg = 0.0f;
  float lreg = 0.0f, ureg = 0.0f, dreg = 0.0f;
  if (t < 128) {
    lreg = lv[(size_t)b * 512 + s * 128 + t];
    ureg = uv[(size_t)b * 512 + s * 128 + t];
    dreg = dvec[(size_t)b * 512 + s * 128 + t];
  }
  wloc[t] = 0.0f;  // w_0 = 0

  unsigned long long* wt0 = wtag + (size_t)b * 512;
  unsigned long long* wt1 = wtag + 32768 + (size_t)b * 512;
  int gr = (s * 128 + t) & 511;
  const float4* wq4 = (const float4*)(wloc + c0);

  for (int it = 0; it < NITERS; ++it) {
    __syncthreads();  // Btop: wloc == w_it everywhere

    float r0a = 0.f, r0b = 0.f, r1a = 0.f, r1b = 0.f;
#pragma unroll
    for (int j = 0; j < 8; ++j) {
      float4 wa = wq4[2 * j];
      float4 wc = wq4[2 * j + 1];
      r0a += G0[8 * j + 0] * wa.x + G0[8 * j + 1] * wa.y +
             G0[8 * j + 2] * wa.z + G0[8 * j + 3] * wa.w;
      r1a += G1[8 * j + 0] * wa.x + G1[8 * j + 1] * wa.y +
             G1[8 * j + 2] * wa.z + G1[8 * j + 3] * wa.w;
      r0b += G0[8 * j + 4] * wc.x + G0[8 * j + 5] * wc.y +
             G0[8 * j + 6] * wc.z + G0[8 * j + 7] * wc.w;
      r1b += G1[8 * j + 4] * wc.x + G1[8 * j + 5] * wc.y +
             G1[8 * j + 6] * wc.z + G1[8 * j + 7] * wc.w;
    }
    part[wv][l] = r0a + r0b;
    part[wv][64 + l] = r1a + r1b;
    __syncthreads();  // B1: partials visible; wloc reads of iter `it` done

    if (t < 128) {
      float w_old = RHO_C * zreg - yreg;
      Sreg = w_old - 0.6f * Sreg;
      float p = part[0][t] + part[1][t] + part[2][t] + part[3][t] +
                part[4][t] + part[5][t] + part[6][t] + part[7][t];
      float zt = p - dreg;
      float zh = ALPHA_C * zt + (1.0f - ALPHA_C) * zreg;
      float zc = zh + yreg * (1.0f / RHO_C);
      zc = fminf(fmaxf(zc, lreg), ureg);
      yreg += RHO_C * (zh - zc);
      zreg = zc;
      float wn = RHO_C * zreg - yreg;
      wloc[s * 128 + t] = wn;
      if (it < NITERS - 1) {
        unsigned long long pk =
            ((unsigned long long)(unsigned)(it + 1) << 32) |
            (unsigned long long)__float_as_uint(wn);
        unsigned long long* wp = ((it + 1) & 1) ? wt1 : wt0;
        __hip_atomic_store(&wp[s * 128 + t], pk, __ATOMIC_RELAXED,
                           __HIP_MEMORY_SCOPE_AGENT);
      }
    } else if (it < NITERS - 1) {
      unsigned long long* wp = ((it + 1) & 1) ? wt1 : wt0;
      unsigned want = (unsigned)(it + 1);
      unsigned long long v;
      for (;;) {
        v = __hip_atomic_load(&wp[gr], __ATOMIC_RELAXED,
                              __HIP_MEMORY_SCOPE_AGENT);
        if ((unsigned)(v >> 32) == want) break;
        __builtin_amdgcn_s_sleep(1);
      }
      wloc[gr] = __uint_as_float((unsigned)(v & 0xffffffffu));
    }
  }

  if (t < 128) Sbuf[(size_t)b * 512 + s * 128 + t] = Sreg;
}

// ---------------------------------------------------------------------------
// K7: epilogue  x = Minv * (alpha * A^T S - q)
// ---------------------------------------------------------------------------
__global__ __launch_bounds__(256) void k_final(
    const float* __restrict__ A, const float* __restrict__ q,
    const float* __restrict__ Mi, const float* __restrict__ Sbuf,
    float* __restrict__ xout) {
  int b = blockIdx.x, t = threadIdx.x;
  __shared__ float Ssh[512];
  __shared__ float uu[256];
  for (int i = t; i < 512; i += 256) Ssh[i] = Sbuf[(size_t)b * 512 + i];
  __syncthreads();
  const float* Ab = A + (size_t)b * 131072;
  float acc = 0.0f;
  for (int m = 0; m < 512; ++m) acc += Ab[(size_t)m * 256 + t] * Ssh[m];
  uu[t] = ALPHA_C * acc - q[(size_t)b * 256 + t];
  __syncthreads();
  const float* Mb = Mi + (size_t)b * 65536;
  float x = 0.0f;
  for (int kk = 0; kk < 256; ++kk) x += Mb[(size_t)kk * 256 + t] * uu[kk];
  xout[(size_t)b * 256 + t] = x;
}

// ---------------------------------------------------------------------------
extern "C" void kernel_launch(void* const* d_in, const int* in_sizes, int n_in,
                              void* d_out, int out_size, void* d_ws, size_t ws_size,
                              hipStream_t stream) {
  (void)in_sizes; (void)n_in; (void)out_size; (void)ws_size;
  const float* P = (const float*)d_in[0];
  const float* q = (const float*)d_in[1];
  const float* Av = (const float*)d_in[2];
  const float* lv = (const float*)d_in[3];
  const float* uv = (const float*)d_in[4];
  float* xout = (float*)d_out;

  float* ws = (float*)d_ws;
  float* At = ws;                       // 64*256*512; dies after F GEMM
  float* F  = ws;                       // alias of At; dies after G GEMM
  float* Mi = ws + 8388608;             // 64*256*256
  float* Mk = ws + 12582912;            // dies after k_invert
  float* G  = ws + 12582912;            // 64*512*512 (over dead Mk)
  float* hv = ws + 29360128;            // 64*256
  float* dv = ws + 29376512;            // 64*512
  float* Sbuf = ws + 29409280;          // 64*512
  unsigned long long* wtag = (unsigned long long*)ws;  // overlays dead At/F

  k_transpose<<<dim3(8, 16, 64), dim3(32, 8), 0, stream>>>(Av, At);
  // Mk = rho*At*At^T + diag(P+sigma): upper tiles only (symN=2 -> 3 tiles)
  k_ntgemm<<<dim3(3, 64), 256, 0, stream>>>(At, At, Mk, 256, 512,
                                            131072LL, 131072LL, 65536LL,
                                            RHO_C, P, 0, 2);
  k_mirror<<<dim3(28, 64), 256, 0, stream>>>(Mk, 256, 65536LL);
  k_invert<<<64, 512, 0, stream>>>(Mk, Mi);
  k_matvec_h<<<64, 256, 0, stream>>>(Mi, q, hv);
  k_matvec_d<<<64, 512, 0, stream>>>(At, hv, dv);
  // F = A * Minv (full: 4x2 tiles)
  k_ntgemm<<<dim3(8, 64), 256, 0, stream>>>(Av, Mi, F, 256, 256,
                                            131072LL, 65536LL, 131072LL,
                                            1.0f, nullptr, 2, 0);
  // G = F * A^T: upper tiles only (symN=4 -> 10 tiles)
  k_ntgemm<<<dim3(10, 64), 256, 0, stream>>>(F, Av, G, 512, 256,
                                             131072LL, 131072LL, 262144LL,
                                             1.0f, nullptr, 0, 4);
  k_mirror<<<dim3(120, 64), 256, 0, stream>>>(G, 512, 262144LL);
  k_admm4<<<256, 512, 0, stream>>>(G, dv, lv, uv, wtag, Sbuf);
  k_final<<<64, 256, 0, stream>>>(Av, q, Mi, Sbuf, xout);
}

// Round 10
// 1722.553 us; speedup vs baseline: 1.0785x; 1.0111x over previous
//
#include <hip/hip_runtime.h>
#include <hip/hip_fp16.h>

#define N_VAR 256
#define M_CON 512
#define BATCH 64
#define SIGMA_C 1e-6f
#define RHO_C 0.1f
#define ALPHA_C 1.6f
#define NITERS 500

// ---------------------------------------------------------------------------
// K1: transpose A [512][256] -> At [256][512] per batch
// ---------------------------------------------------------------------------
__global__ __launch_bounds__(256) void k_transpose(const float* __restrict__ A,
                                                   float* __restrict__ At) {
  __shared__ float tile[32][33];
  int b = blockIdx.z;
  int n0 = blockIdx.x * 32;
  int m0 = blockIdx.y * 32;
  const float* Ab = A + (size_t)b * (M_CON * N_VAR);
  float* Atb = At + (size_t)b * (M_CON * N_VAR);
  int tx = threadIdx.x, ty = threadIdx.y;  // (32, 8)
#pragma unroll
  for (int j = 0; j < 32; j += 8)
    tile[ty + j][tx] = Ab[(size_t)(m0 + ty + j) * N_VAR + n0 + tx];
  __syncthreads();
#pragma unroll
  for (int j = 0; j < 32; j += 8)
    Atb[(size_t)(n0 + ty + j) * M_CON + m0 + tx] = tile[tx][ty + j];
}

// ---------------------------------------------------------------------------
// K2: batched NT GEMM, double-buffered LDS, PADDED row dim (128->132) to kill
// the 4-way staging-store bank conflicts (round-9: SQ_LDS_BANK_CONFLICT
// 1.65e7 -> banks (k40*132+row)%32 = (4*k40+row)%32, 2-way max = free).
// symN>0: upper tiles only; k_mirror fills the rest.
// ---------------------------------------------------------------------------
__global__ __launch_bounds__(256) void k_ntgemm(
    const float* __restrict__ X, const float* __restrict__ Y,
    float* __restrict__ C, int J, int K,
    long long bsX, long long bsY, long long bsC, float alpha,
    const float* __restrict__ diagv, int tilesJ, int symN) {
  int b = blockIdx.y;
  int ti, tj;
  if (symN > 0) {
    int r = blockIdx.x;
    ti = 0;
    while (r >= symN - ti) { r -= (symN - ti); ++ti; }
    tj = ti + r;
  } else {
    ti = blockIdx.x / tilesJ;
    tj = blockIdx.x % tilesJ;
  }
  int i0 = ti * 128, j0 = tj * 128;
  const float* Xb = X + (size_t)b * bsX;
  const float* Yb = Y + (size_t)b * bsY;
  float* Cb = C + (size_t)b * bsC;
  __shared__ float Xs[2][16][132];
  __shared__ float Ys[2][16][132];
  int tid = threadIdx.x;
  int tx = tid & 15, ty = tid >> 4;
  int row0 = tid >> 2, k40 = (tid & 3) * 4;

  float acc[8][8];
#pragma unroll
  for (int r = 0; r < 8; ++r)
#pragma unroll
    for (int c = 0; c < 8; ++c) acc[r][c] = 0.0f;

  float4 rx0, rx1, ry0, ry1;
  auto prefetch = [&](int kk) {
    rx0 = *(const float4*)(Xb + (size_t)(i0 + row0) * K + kk + k40);
    rx1 = *(const float4*)(Xb + (size_t)(i0 + row0 + 64) * K + kk + k40);
    ry0 = *(const float4*)(Yb + (size_t)(j0 + row0) * K + kk + k40);
    ry1 = *(const float4*)(Yb + (size_t)(j0 + row0 + 64) * K + kk + k40);
  };
  auto commit = [&](int buf) {
    Xs[buf][k40 + 0][row0] = rx0.x; Xs[buf][k40 + 1][row0] = rx0.y;
    Xs[buf][k40 + 2][row0] = rx0.z; Xs[buf][k40 + 3][row0] = rx0.w;
    Xs[buf][k40 + 0][row0 + 64] = rx1.x; Xs[buf][k40 + 1][row0 + 64] = rx1.y;
    Xs[buf][k40 + 2][row0 + 64] = rx1.z; Xs[buf][k40 + 3][row0 + 64] = rx1.w;
    Ys[buf][k40 + 0][row0] = ry0.x; Ys[buf][k40 + 1][row0] = ry0.y;
    Ys[buf][k40 + 2][row0] = ry0.z; Ys[buf][k40 + 3][row0] = ry0.w;
    Ys[buf][k40 + 0][row0 + 64] = ry1.x; Ys[buf][k40 + 1][row0 + 64] = ry1.y;
    Ys[buf][k40 + 2][row0 + 64] = ry1.z; Ys[buf][k40 + 3][row0 + 64] = ry1.w;
  };

  int nkt = K >> 4;
  prefetch(0);
  commit(0);
  __syncthreads();

  for (int kt = 0; kt < nkt; ++kt) {
    int cur = kt & 1;
    if (kt + 1 < nkt) prefetch((kt + 1) * 16);
#pragma unroll
    for (int k = 0; k < 16; ++k) {
      float xr[8], yr[8];
      *(float4*)&xr[0] = *(float4*)&Xs[cur][k][ty * 8];
      *(float4*)&xr[4] = *(float4*)&Xs[cur][k][ty * 8 + 4];
      *(float4*)&yr[0] = *(float4*)&Ys[cur][k][tx * 8];
      *(float4*)&yr[4] = *(float4*)&Ys[cur][k][tx * 8 + 4];
#pragma unroll
      for (int r = 0; r < 8; ++r)
#pragma unroll
        for (int c = 0; c < 8; ++c) acc[r][c] += xr[r] * yr[c];
    }
    if (kt + 1 < nkt) commit(cur ^ 1);
    __syncthreads();
  }

#pragma unroll
  for (int r = 0; r < 8; ++r) {
    int gi = i0 + ty * 8 + r;
#pragma unroll
    for (int c = 0; c < 8; ++c) {
      int gj = j0 + tx * 8 + c;
      float val = acc[r][c] * alpha;
      if (diagv != nullptr && gi == gj) val += diagv[(size_t)b * N_VAR + gi] + SIGMA_C;
      Cb[(size_t)gi * J + gj] = val;
    }
  }
}

// ---------------------------------------------------------------------------
// K2b: mirror upper triangle -> lower for symmetric n x n.
// ---------------------------------------------------------------------------
__global__ __launch_bounds__(256) void k_mirror(float* __restrict__ C, int n,
                                                long long bsC) {
  __shared__ float tile[32][33];
  int b = blockIdx.y;
  int idx = blockIdx.x;
  int bi = 1;
  while (idx >= bi) { idx -= bi; ++bi; }
  int bj = idx;
  float* Cb = C + (size_t)b * bsC;
  int tx = threadIdx.x & 31, ty = threadIdx.x >> 5;  // 32 x 8
#pragma unroll
  for (int j = 0; j < 32; j += 8)
    tile[ty + j][tx] = Cb[(size_t)(bj * 32 + ty + j) * n + bi * 32 + tx];
  __syncthreads();
#pragma unroll
  for (int j = 0; j < 32; j += 8)
    Cb[(size_t)(bi * 32 + ty + j) * n + bj * 32 + tx] = tile[tx][ty + j];
}

// ---------------------------------------------------------------------------
// K3: BLOCKED Gauss-Jordan inversion, NB=8 (round-7 version).
// ---------------------------------------------------------------------------
__global__ __launch_bounds__(512, 2) void k_invert(const float* __restrict__ Mk,
                                                   float* __restrict__ Mi) {
  int b = blockIdx.x;
  const float* src = Mk + (size_t)b * 65536;
  float* dst = Mi + (size_t)b * 65536;
  int t = threadIdx.x;
  int c = t & 255, rh = t >> 8;

  float a[128];
#pragma unroll
  for (int j = 0; j < 128; ++j) a[j] = src[(size_t)(rh * 128 + j) * 256 + c];

  __shared__ float colPan[256][8];
  __shared__ float rowPan[2][8][260];
  __shared__ float PiSh[64];
  __shared__ float Rp[8][260];

  int rh_s = __builtin_amdgcn_readfirstlane(rh);
  int cw_s = __builtin_amdgcn_readfirstlane((t >> 6) & 3);

  if (rh == 0) {
#pragma unroll
    for (int j = 0; j < 8; ++j) rowPan[0][j][c] = a[j];
  }
  __syncthreads();

  for (int s = 0; s < 32; ++s) {
    int kb = s * 8;
    int cur = s & 1, nxt = cur ^ 1;
    int kh = kb >> 7, kj = kb & 127;
    int khn = (kb + 8) >> 7, kjn = (kb + 8) & 127;
    bool mycol = (c >= kb) && (c < kb + 8);

    if (cw_s == (kb >> 6)) {
      if (mycol) {
        int f = c - kb;
#pragma unroll
        for (int j = 0; j < 128; ++j) colPan[rh * 128 + j][f] = a[j];
      }
    }
    if (t < 64) {
      int e = t >> 3, f = t & 7;
      float p = rowPan[cur][e][kb + f];
#pragma unroll
      for (int k2 = 0; k2 < 8; ++k2) {
        float piv = __shfl(p, k2 * 8 + k2);
        float rv = __shfl(p, k2 * 8 + f);
        float cv = __shfl(p, e * 8 + k2);
        float pivinv = 1.0f / piv;
        float srv = rv * pivinv;
        float gen = p - cv * srv;
        p = gen;
        if (e == k2) p = srv;
        if (f == k2) p = -cv * pivinv;
        if (e == k2 && f == k2) p = pivinv;
      }
      PiSh[t] = p;
    }
    __syncthreads();

    float rpan[8];
#pragma unroll
    for (int f2 = 0; f2 < 8; ++f2) rpan[f2] = rowPan[cur][f2][c];
    float rp[8];
#pragma unroll
    for (int e = 0; e < 8; ++e) {
      float4 p0 = *(const float4*)&PiSh[e * 8];
      float4 p1 = *(const float4*)&PiSh[e * 8 + 4];
      rp[e] = p0.x * rpan[0] + p0.y * rpan[1] + p0.z * rpan[2] + p0.w * rpan[3] +
              p1.x * rpan[4] + p1.y * rpan[5] + p1.z * rpan[6] + p1.w * rpan[7];
    }
    if (cw_s == (kb >> 6)) {
      if (mycol) {
        int f = c - kb;
#pragma unroll
        for (int e = 0; e < 8; ++e) rp[e] = PiSh[e * 8 + f];
      }
    }
#pragma unroll
    for (int e = 0; e < 8; ++e) Rp[e][c] = rp[e];

    bool myhalfk = (rh_s == kh);
    bool stashw = (s != 31) && (rh_s == khn);
#pragma unroll
    for (int j = 0; j < 128; ++j) {
      float4 c0 = *(const float4*)&colPan[rh * 128 + j][0];
      float4 c1 = *(const float4*)&colPan[rh * 128 + j][4];
      float aold = a[j];
      float nv = aold -
                 (c0.x * rp[0] + c0.y * rp[1] + c0.z * rp[2] + c0.w * rp[3] +
                  c1.x * rp[4] + c1.y * rp[5] + c1.z * rp[6] + c1.w * rp[7]);
      if (mycol) nv -= aold;
      if (myhalfk && j >= kj && j < kj + 8)
        nv = Rp[j - kj][c];
      a[j] = nv;
      if (stashw && j >= kjn && j < kjn + 8)
        rowPan[nxt][j - kjn][c] = nv;
    }
    __syncthreads();
  }

#pragma unroll
  for (int j = 0; j < 128; ++j) dst[(size_t)(rh * 128 + j) * 256 + c] = a[j];
}

// ---------------------------------------------------------------------------
// K4a: h = Minv * q  (column access via symmetry)
// ---------------------------------------------------------------------------
__global__ __launch_bounds__(256) void k_matvec_h(const float* __restrict__ Mi,
                                                  const float* __restrict__ q,
                                                  float* __restrict__ h) {
  int b = blockIdx.x, t = threadIdx.x;
  __shared__ float qs[256];
  qs[t] = q[(size_t)b * 256 + t];
  __syncthreads();
  const float* Mb = Mi + (size_t)b * 65536;
  float acc = 0.0f;
  for (int k = 0; k < 256; ++k) acc += Mb[(size_t)k * 256 + t] * qs[k];
  h[(size_t)b * 256 + t] = acc;
}

// K4b: d = A * h  via At columns
__global__ __launch_bounds__(512) void k_matvec_d(const float* __restrict__ At,
                                                  const float* __restrict__ h,
                                                  float* __restrict__ d) {
  int b = blockIdx.x, t = threadIdx.x;
  __shared__ float hs[256];
  if (t < 256) hs[t] = h[(size_t)b * 256 + t];
  __syncthreads();
  const float* Ab = At + (size_t)b * 131072;
  float acc = 0.0f;
  for (int n = 0; n < 256; ++n) acc += Ab[(size_t)n * 512 + t] * hs[n];
  d[(size_t)b * 512 + t] = acc;
}

// ---------------------------------------------------------------------------
// K6: ADMM loop, 4 CUs/batch, register-resident G, packed (tag|value) u64
// relaxed agent-atomic exchange (round-6/7 transport). NEW GEMV MAPPING:
// thread (r=t&31, c=t>>5) owns rows {r,r+32,r+64,r+96} x cols [c*32,c*32+32)
// -> w reads halve to 8 ds_read_b128/thread (half-wave-uniform address =
// 2-way = free); partials in part[16][132] (pad -> conflict-free).
// Same 128 G-regs, same FMA count, ~0.3 us/iter less LDS time.
// ---------------------------------------------------------------------------
__global__ __launch_bounds__(512, 2) void k_admm4(
    const float* __restrict__ G, const float* __restrict__ dvec,
    const float* __restrict__ lv, const float* __restrict__ uv,
    unsigned long long* __restrict__ wtag, float* __restrict__ Sbuf) {
  int g = blockIdx.x;
  int b = (g & 7) + 8 * ((g >> 3) & 7);
  int s = g >> 6;
  int t = threadIdx.x;
  int r = t & 31, ck = t >> 5;    // row-in-group, col chunk (half-wave uniform)
  int c0 = ck * 32;

  __shared__ __align__(16) float wloc[512];
  __shared__ float part[16][132];

  // --- one-time: G strip into registers (rows r+32k, cols [c0,c0+32)) ---
  const float* Gb = G + (size_t)b * 262144;
  float Greg[4][32];
#pragma unroll
  for (int k = 0; k < 4; ++k) {
    const float* gp = Gb + (size_t)(s * 128 + r + 32 * k) * 512 + c0;
#pragma unroll
    for (int j = 0; j < 8; ++j) {
      float4 v = *(const float4*)(gp + 4 * j);
      Greg[k][4 * j + 0] = v.x; Greg[k][4 * j + 1] = v.y;
      Greg[k][4 * j + 2] = v.z; Greg[k][4 * j + 3] = v.w;
    }
  }

  float zreg = 0.0f, yreg = 0.0f, Sreg = 0.0f;
  float lreg = 0.0f, ureg = 0.0f, dreg = 0.0f;
  if (t < 128) {
    lreg = lv[(size_t)b * 512 + s * 128 + t];
    ureg = uv[(size_t)b * 512 + s * 128 + t];
    dreg = dvec[(size_t)b * 512 + s * 128 + t];
  }
  wloc[t] = 0.0f;  // w_0 = 0

  unsigned long long* wt0 = wtag + (size_t)b * 512;
  unsigned long long* wt1 = wtag + 32768 + (size_t)b * 512;
  int gr = (s * 128 + t) & 511;   // poll target (t>=128: the 384 remote rows)
  const float4* wq4 = (const float4*)(wloc + c0);

  for (int it = 0; it < NITERS; ++it) {
    __syncthreads();  // Btop: wloc == w_it everywhere

    // partial zt: rows {r,r+32,r+64,r+96}, cols [c0,c0+32)
    float a0 = 0.f, a1 = 0.f, a2 = 0.f, a3 = 0.f;
#pragma unroll
    for (int j = 0; j < 8; ++j) {
      float4 w4 = wq4[j];  // half-wave-uniform ds_read_b128 (2-way = free)
      a0 += Greg[0][4 * j + 0] * w4.x + Greg[0][4 * j + 1] * w4.y +
            Greg[0][4 * j + 2] * w4.z + Greg[0][4 * j + 3] * w4.w;
      a1 += Greg[1][4 * j + 0] * w4.x + Greg[1][4 * j + 1] * w4.y +
            Greg[1][4 * j + 2] * w4.z + Greg[1][4 * j + 3] * w4.w;
      a2 += Greg[2][4 * j + 0] * w4.x + Greg[2][4 * j + 1] * w4.y +
            Greg[2][4 * j + 2] * w4.z + Greg[2][4 * j + 3] * w4.w;
      a3 += Greg[3][4 * j + 0] * w4.x + Greg[3][4 * j + 1] * w4.y +
            Greg[3][4 * j + 2] * w4.z + Greg[3][4 * j + 3] * w4.w;
    }
    part[ck][r] = a0;
    part[ck][r + 32] = a1;
    part[ck][r + 64] = a2;
    part[ck][r + 96] = a3;
    __syncthreads();  // B1: partials visible; wloc reads of iter `it` done

    if (t < 128) {
      float w_old = RHO_C * zreg - yreg;
      Sreg = w_old - 0.6f * Sreg;       // S <- w + (1-alpha)*S
      float p = 0.0f;
#pragma unroll
      for (int c = 0; c < 16; ++c) p += part[c][t];
      float zt = p - dreg;
      float zh = ALPHA_C * zt + (1.0f - ALPHA_C) * zreg;
      float zc = zh + yreg * (1.0f / RHO_C);
      zc = fminf(fmaxf(zc, lreg), ureg);
      yreg += RHO_C * (zh - zc);
      zreg = zc;
      float wn = RHO_C * zreg - yreg;   // w_{it+1}[own row]
      wloc[s * 128 + t] = wn;
      if (it < NITERS - 1) {
        unsigned long long pk =
            ((unsigned long long)(unsigned)(it + 1) << 32) |
            (unsigned long long)__float_as_uint(wn);
        unsigned long long* wp = ((it + 1) & 1) ? wt1 : wt0;
        __hip_atomic_store(&wp[s * 128 + t], pk, __ATOMIC_RELAXED,
                           __HIP_MEMORY_SCOPE_AGENT);
      }
    } else if (it < NITERS - 1) {
      unsigned long long* wp = ((it + 1) & 1) ? wt1 : wt0;
      unsigned want = (unsigned)(it + 1);
      unsigned long long v;
      for (;;) {
        v = __hip_atomic_load(&wp[gr], __ATOMIC_RELAXED,
                              __HIP_MEMORY_SCOPE_AGENT);
        if ((unsigned)(v >> 32) == want) break;
        __builtin_amdgcn_s_sleep(1);
      }
      wloc[gr] = __uint_as_float((unsigned)(v & 0xffffffffu));
    }
  }

  if (t < 128) Sbuf[(size_t)b * 512 + s * 128 + t] = Sreg;
}

// ---------------------------------------------------------------------------
// K7: epilogue  x = Minv * (alpha * A^T S - q)
// ---------------------------------------------------------------------------
__global__ __launch_bounds__(256) void k_final(
    const float* __restrict__ A, const float* __restrict__ q,
    const float* __restrict__ Mi, const float* __restrict__ Sbuf,
    float* __restrict__ xout) {
  int b = blockIdx.x, t = threadIdx.x;
  __shared__ float Ssh[512];
  __shared__ float uu[256];
  for (int i = t; i < 512; i += 256) Ssh[i] = Sbuf[(size_t)b * 512 + i];
  __syncthreads();
  const float* Ab = A + (size_t)b * 131072;
  float acc = 0.0f;
  for (int m = 0; m < 512; ++m) acc += Ab[(size_t)m * 256 + t] * Ssh[m];
  uu[t] = ALPHA_C * acc - q[(size_t)b * 256 + t];
  __syncthreads();
  const float* Mb = Mi + (size_t)b * 65536;
  float x = 0.0f;
  for (int kk = 0; kk < 256; ++kk) x += Mb[(size_t)kk * 256 + t] * uu[kk];
  xout[(size_t)b * 256 + t] = x;
}

// ---------------------------------------------------------------------------
extern "C" void kernel_launch(void* const* d_in, const int* in_sizes, int n_in,
                              void* d_out, int out_size, void* d_ws, size_t ws_size,
                              hipStream_t stream) {
  (void)in_sizes; (void)n_in; (void)out_size; (void)ws_size;
  const float* P = (const float*)d_in[0];
  const float* q = (const float*)d_in[1];
  const float* Av = (const float*)d_in[2];
  const float* lv = (const float*)d_in[3];
  const float* uv = (const float*)d_in[4];
  float* xout = (float*)d_out;

  float* ws = (float*)d_ws;
  float* At = ws;                       // 64*256*512; dies after F GEMM
  float* F  = ws;                       // alias of At; dies after G GEMM
  float* Mi = ws + 8388608;             // 64*256*256
  float* Mk = ws + 12582912;            // dies after k_invert
  float* G  = ws + 12582912;            // 64*512*512 (over dead Mk)
  float* hv = ws + 29360128;            // 64*256
  float* dv = ws + 29376512;            // 64*512
  float* Sbuf = ws + 29409280;          // 64*512
  unsigned long long* wtag = (unsigned long long*)ws;  // overlays dead At/F

  k_transpose<<<dim3(8, 16, 64), dim3(32, 8), 0, stream>>>(Av, At);
  // Mk = rho*At*At^T + diag(P+sigma): upper tiles only (symN=2 -> 3 tiles)
  k_ntgemm<<<dim3(3, 64), 256, 0, stream>>>(At, At, Mk, 256, 512,
                                            131072LL, 131072LL, 65536LL,
                                            RHO_C, P, 0, 2);
  k_mirror<<<dim3(28, 64), 256, 0, stream>>>(Mk, 256, 65536LL);
  k_invert<<<64, 512, 0, stream>>>(Mk, Mi);
  k_matvec_h<<<64, 256, 0, stream>>>(Mi, q, hv);
  k_matvec_d<<<64, 512, 0, stream>>>(At, hv, dv);
  // F = A * Minv (full: 4x2 tiles)
  k_ntgemm<<<dim3(8, 64), 256, 0, stream>>>(Av, Mi, F, 256, 256,
                                            131072LL, 65536LL, 131072LL,
                                            1.0f, nullptr, 2, 0);
  // G = F * A^T: upper tiles only (symN=4 -> 10 tiles)
  k_ntgemm<<<dim3(10, 64), 256, 0, stream>>>(F, Av, G, 512, 256,
                                             131072LL, 131072LL, 262144LL,
                                             1.0f, nullptr, 0, 4);
  k_mirror<<<dim3(120, 64), 256, 0, stream>>>(G, 512, 262144LL);
  k_admm4<<<256, 512, 0, stream>>>(G, dv, lv, uv, wtag, Sbuf);
  k_final<<<64, 256, 0, stream>>>(Av, q, Mi, Sbuf, xout);
}